// Round 2
// baseline (124.126 us; speedup 1.0000x reference)
//
#include <hip/hip_runtime.h>
#include <hip/hip_bf16.h>

// Problem constants (B=2, H=16, L=2048, D=E=64)
#define BH_  32
#define H_   16
#define L_   2048
#define D_   64
#define NC_  32      // number of 64-row chunks per (b,h)
#define STR  72      // LDS row stride in halfs (64 + 8 pad -> 144B rows, 2-way banks)

typedef _Float16 half8  __attribute__((ext_vector_type(8)));
typedef float    floatx4 __attribute__((ext_vector_type(4)));

#define MFMA(a, b, c) __builtin_amdgcn_mfma_f32_16x16x32_f16((a), (b), (c), 0, 0, 0)

// Load an MFMA operand fragment from a row-major [rows][K] LDS matrix.
// A-operand: rows = m; B-operand: rows = n (matrix stored as B^T).
// lane layout: row = row0 + (lane&15), k = k0 + (lane>>4)*8 .. +7 (contiguous 16B)
__device__ __forceinline__ half8 ldfrag(const _Float16* p, int row0, int k0) {
    const int lane = threadIdx.x & 63;
    const _Float16* q = p + (row0 + (lane & 15)) * STR + k0 + ((lane >> 4) << 3);
    return *(const half8*)q;
}

// ---------------------------------------------------------------------------
// Kernel A: per-chunk state sums.  block (c, bh):
//   kf = relu(K_chunk @ Wk[h])      (MFMA, f16)
//   S_c[d][e] = sum_n kf[n][d] V[n][e]   -> Scs
//   z_c[d]    = sum_n kf[n][d]           -> zc
// kf precision: single f16 is sufficient — kf rounding errors enter the
// output either qf-scaled (cancel in num/den ratio) or as tiny absolute
// perturbations of S/z (0.2 out of 3700).
// ---------------------------------------------------------------------------
__global__ __launch_bounds__(256, 2)
void ka_chunksum(const float* __restrict__ K, const float* __restrict__ V,
                 const float* __restrict__ Wk,
                 float* __restrict__ Scs, float* __restrict__ zc) {
    __shared__ _Float16 sKin[64 * STR];  // K chunk, [n][d]
    __shared__ _Float16 sWT [64 * STR];  // Wk^T,    [e][d]
    __shared__ _Float16 sKT [64 * STR];  // kf^T,    [d][n]
    __shared__ _Float16 sVT [64 * STR];  // V^T,     [e][n]

    const int c = blockIdx.x, bh = blockIdx.y, h = bh & (H_ - 1);
    const int tid = threadIdx.x, lane = tid & 63, w = tid >> 6;
    const int quad = lane >> 4, cl = lane & 15;

    const float* Kg = K + ((size_t)bh * L_ + c * 64) * D_;
    const float* Vg = V + ((size_t)bh * L_ + c * 64) * D_;
    const float* Wg = Wk + (size_t)h * 4096;

    for (int i = 0; i < 16; ++i) {
        int flat = i * 256 + tid;
        int r = flat >> 6, e = flat & 63;
        sKin[r * STR + e] = (_Float16)Kg[flat];
        sWT [e * STR + r] = (_Float16)Wg[flat];   // W[d][e] -> [e][d]
        sVT [e * STR + r] = (_Float16)Vg[flat];   // V[n][e] -> [e][n]
    }
    __syncthreads();

    // kf = relu(Kin @ Wk); write transposed into sKT[d][n]
    half8 a0 = ldfrag(sKin, w * 16, 0), a1 = ldfrag(sKin, w * 16, 32);
    for (int et = 0; et < 4; ++et) {
        floatx4 acc = {0.f, 0.f, 0.f, 0.f};
        acc = MFMA(a0, ldfrag(sWT, et * 16, 0),  acc);
        acc = MFMA(a1, ldfrag(sWT, et * 16, 32), acc);
        #pragma unroll
        for (int r = 0; r < 4; ++r) {
            float v = acc[r] > 0.f ? acc[r] : 0.f;
            // value is kf[n = w*16+quad*4+r][d = et*16+cl]
            sKT[(et * 16 + cl) * STR + (w * 16 + quad * 4 + r)] = (_Float16)v;
        }
    }
    __syncthreads();

    if (tid < 64) {  // z_c[d] = sum_n kf[n][d]
        float s = 0.f;
        for (int n = 0; n < 64; ++n) s += (float)sKT[tid * STR + n];
        zc[((size_t)bh * NC_ + c) * 64 + tid] = s;
    }

    // S_c = kf^T @ V : M=d (sKT rows), N=e (sVT rows), K=n
    float* So = Scs + ((size_t)bh * NC_ + c) * 4096;
    half8 t0 = ldfrag(sKT, w * 16, 0), t1 = ldfrag(sKT, w * 16, 32);
    for (int et = 0; et < 4; ++et) {
        floatx4 acc = {0.f, 0.f, 0.f, 0.f};
        acc = MFMA(t0, ldfrag(sVT, et * 16, 0),  acc);
        acc = MFMA(t1, ldfrag(sVT, et * 16, 32), acc);
        #pragma unroll
        for (int r = 0; r < 4; ++r)
            So[(w * 16 + quad * 4 + r) * 64 + et * 16 + cl] = acc[r];
    }
}

// ---------------------------------------------------------------------------
// Kernel P: in-place EXCLUSIVE prefix sum over chunks for Scs and zc.
// ---------------------------------------------------------------------------
__global__ __launch_bounds__(64)
void kp_prefix(float* __restrict__ Scs, float* __restrict__ zc) {
    const int bid = blockIdx.x, t = threadIdx.x;
    if (bid < BH_ * 64) {
        const int bh = bid >> 6, d = bid & 63;
        size_t base = (size_t)bh * NC_ * 4096 + (size_t)d * 64 + t;
        float run = 0.f;
        #pragma unroll
        for (int c = 0; c < NC_; ++c) {
            float v = Scs[base + (size_t)c * 4096];
            Scs[base + (size_t)c * 4096] = run;
            run += v;
        }
    } else {
        const int bh = bid - BH_ * 64;
        size_t base = (size_t)bh * NC_ * 64 + t;
        float run = 0.f;
        #pragma unroll
        for (int c = 0; c < NC_; ++c) {
            float v = zc[base + c * 64];
            zc[base + c * 64] = run;
            run += v;
        }
    }
}

// ---------------------------------------------------------------------------
// Kernel B: per-chunk output, with SPLIT-PRECISION q feature map.
//   qf = relu((Qhi+Qlo)@(Whi+Wlo))  ~fp32 accuracy  (3 MFMAs per k-seg)
//   den_prefix = qf . z  computed from fp32 accumulators (no f16 round-trip)
//   qf stored to LDS as (hi,lo) f16 pair; used split in QK^T and qf@S.
//   kf single-f16 (errors qbar-cancelling).
// ---------------------------------------------------------------------------
__global__ __launch_bounds__(256, 2)
void kb_attn(const float* __restrict__ Q, const float* __restrict__ K,
             const float* __restrict__ V, const float* __restrict__ Wq,
             const float* __restrict__ Wk, const float* __restrict__ Sst,
             const float* __restrict__ zs, float* __restrict__ Out) {
    __shared__ _Float16 sQh[64 * STR];  // Q hi [m][d]   -> qf hi [m][e]
    __shared__ _Float16 sQl[64 * STR];  // Q lo [m][d]   -> qf lo [m][e]
    __shared__ _Float16 sWh[64 * STR];  // Wq hi^T [e][d] -> Wk hi^T
    __shared__ _Float16 sWl[64 * STR];  // Wq lo^T [e][d] -> P [m][n]
    __shared__ _Float16 sVT[64 * STR];  // V^T [e][n]
    __shared__ _Float16 sST[64 * STR];  // S_prefix^T [e][d]
    __shared__ _Float16 sKB[64 * STR];  // K [n][d]      -> kf [n][e]
    __shared__ float sZ[64];
    __shared__ float sInv[64];

    const int c = blockIdx.x, bh = blockIdx.y, h = bh & (H_ - 1);
    const int tid = threadIdx.x, lane = tid & 63, w = tid >> 6;
    const int quad = lane >> 4, cl = lane & 15;

    const float* Qg = Q + ((size_t)bh * L_ + c * 64) * D_;
    const float* Kg = K + ((size_t)bh * L_ + c * 64) * D_;
    const float* Vg = V + ((size_t)bh * L_ + c * 64) * D_;
    const float* Wqg = Wq + (size_t)h * 4096;
    const float* Wkg = Wk + (size_t)h * 4096;
    const float* Sg = Sst + ((size_t)bh * NC_ + c) * 4096;
    const float* Zg = zs + ((size_t)bh * NC_ + c) * 64;

    for (int i = 0; i < 16; ++i) {
        int flat = i * 256 + tid;
        int r = flat >> 6, e = flat & 63;
        float q = Qg[flat];
        _Float16 qh = (_Float16)q;
        sQh[r * STR + e] = qh;
        sQl[r * STR + e] = (_Float16)(q - (float)qh);
        float wv = Wqg[flat];
        _Float16 wh = (_Float16)wv;
        sWh[e * STR + r] = wh;                       // [e][d]
        sWl[e * STR + r] = (_Float16)(wv - (float)wh);
        sKB[r * STR + e] = (_Float16)Kg[flat];
        sVT[e * STR + r] = (_Float16)Vg[flat];
        sST[e * STR + r] = (_Float16)Sg[flat];
    }
    if (tid < 64) sZ[tid] = Zg[tid];
    __syncthreads();

    // --- qf stage: qf = relu(Q@Wq) in ~fp32; dq = qf . z from fp32 accs ---
    half8 aqh0 = ldfrag(sQh, w * 16, 0), aqh1 = ldfrag(sQh, w * 16, 32);
    half8 aql0 = ldfrag(sQl, w * 16, 0), aql1 = ldfrag(sQl, w * 16, 32);
    float dq[4] = {0.f, 0.f, 0.f, 0.f};
    for (int et = 0; et < 4; ++et) {
        half8 bh0 = ldfrag(sWh, et * 16, 0), bh1 = ldfrag(sWh, et * 16, 32);
        half8 bl0 = ldfrag(sWl, et * 16, 0), bl1 = ldfrag(sWl, et * 16, 32);
        floatx4 acc = {0.f, 0.f, 0.f, 0.f};
        acc = MFMA(aqh0, bh0, acc);
        acc = MFMA(aqh1, bh1, acc);
        acc = MFMA(aqh0, bl0, acc);
        acc = MFMA(aqh1, bl1, acc);
        acc = MFMA(aql0, bh0, acc);
        acc = MFMA(aql1, bh1, acc);
        float zv = sZ[et * 16 + cl];
        #pragma unroll
        for (int r = 0; r < 4; ++r) {
            float v = acc[r] > 0.f ? acc[r] : 0.f;
            dq[r] += v * zv;
            _Float16 hi = (_Float16)v;
            // overwrite own rows (a-frags already in regs)
            sQh[(w * 16 + quad * 4 + r) * STR + et * 16 + cl] = hi;
            sQl[(w * 16 + quad * 4 + r) * STR + et * 16 + cl] = (_Float16)(v - (float)hi);
        }
    }
    #pragma unroll
    for (int r = 0; r < 4; ++r) {   // full row-dot across the 16 cl lanes
        dq[r] += __shfl_xor(dq[r], 1);
        dq[r] += __shfl_xor(dq[r], 2);
        dq[r] += __shfl_xor(dq[r], 4);
        dq[r] += __shfl_xor(dq[r], 8);
    }
    __syncthreads();

    // --- restage sWh with Wk hi; sWl becomes the P buffer ---
    for (int i = 0; i < 16; ++i) {
        int flat = i * 256 + tid;
        int r = flat >> 6, e = flat & 63;
        sWh[e * STR + r] = (_Float16)Wkg[flat];
    }
    __syncthreads();

    // --- kf stage: kf = relu(K@Wk), single f16 ---
    half8 ak0 = ldfrag(sKB, w * 16, 0), ak1 = ldfrag(sKB, w * 16, 32);
    for (int et = 0; et < 4; ++et) {
        floatx4 acc = {0.f, 0.f, 0.f, 0.f};
        acc = MFMA(ak0, ldfrag(sWh, et * 16, 0),  acc);
        acc = MFMA(ak1, ldfrag(sWh, et * 16, 32), acc);
        #pragma unroll
        for (int r = 0; r < 4; ++r) {
            float v = acc[r] > 0.f ? acc[r] : 0.f;
            sKB[(w * 16 + quad * 4 + r) * STR + et * 16 + cl] = (_Float16)v;
        }
    }
    __syncthreads();

    // --- phase 1: intra-chunk causal scores P, rowsums, denominators ---
    half8 qh0 = ldfrag(sQh, w * 16, 0), qh1 = ldfrag(sQh, w * 16, 32);
    half8 ql0 = ldfrag(sQl, w * 16, 0), ql1 = ldfrag(sQl, w * 16, 32);
    _Float16* P = sWl;                   // reuse Wq-lo buffer
    float rs[4] = {0.f, 0.f, 0.f, 0.f};
    for (int nt = 0; nt <= w; ++nt) {
        half8 b0 = ldfrag(sKB, nt * 16, 0), b1 = ldfrag(sKB, nt * 16, 32);
        floatx4 acc = {0.f, 0.f, 0.f, 0.f};
        acc = MFMA(qh0, b0, acc);
        acc = MFMA(qh1, b1, acc);
        acc = MFMA(ql0, b0, acc);
        acc = MFMA(ql1, b1, acc);
        #pragma unroll
        for (int r = 0; r < 4; ++r) {
            float v = acc[r];
            if (nt == w && cl > quad * 4 + r) v = 0.f;  // causal mask (diag tile)
            rs[r] += v;
            P[(w * 16 + quad * 4 + r) * STR + nt * 16 + cl] = (_Float16)v;
        }
    }
    for (int nt = w + 1; nt < 4; ++nt) {
        #pragma unroll
        for (int r = 0; r < 4; ++r)
            P[(w * 16 + quad * 4 + r) * STR + nt * 16 + cl] = (_Float16)0.f;
    }
    #pragma unroll
    for (int r = 0; r < 4; ++r) {
        float s = rs[r];
        s += __shfl_xor(s, 1);
        s += __shfl_xor(s, 2);
        s += __shfl_xor(s, 4);
        s += __shfl_xor(s, 8);
        if (cl == 0) sInv[w * 16 + quad * 4 + r] = 1.f / (s + dq[r] + 1e-6f);
    }
    __syncthreads();

    // --- phase 2: O = (qh+ql)@S_prefix + P@V ; scale; store ---
    half8 p0 = ldfrag(P, w * 16, 0), p1 = ldfrag(P, w * 16, 32);
    float inv[4];
    #pragma unroll
    for (int r = 0; r < 4; ++r) inv[r] = sInv[w * 16 + quad * 4 + r];

    float* Og = Out + ((size_t)bh * L_ + c * 64) * D_;
    for (int et = 0; et < 4; ++et) {
        floatx4 acc = {0.f, 0.f, 0.f, 0.f};
        acc = MFMA(qh0, ldfrag(sST, et * 16, 0),  acc);
        acc = MFMA(qh1, ldfrag(sST, et * 16, 32), acc);
        acc = MFMA(ql0, ldfrag(sST, et * 16, 0),  acc);
        acc = MFMA(ql1, ldfrag(sST, et * 16, 32), acc);
        acc = MFMA(p0,  ldfrag(sVT, et * 16, 0),  acc);
        acc = MFMA(p1,  ldfrag(sVT, et * 16, 32), acc);
        #pragma unroll
        for (int r = 0; r < 4; ++r)
            Og[(w * 16 + quad * 4 + r) * 64 + et * 16 + cl] = acc[r] * inv[r];
    }
}

// ---------------------------------------------------------------------------
extern "C" void kernel_launch(void* const* d_in, const int* in_sizes, int n_in,
                              void* d_out, int out_size, void* d_ws, size_t ws_size,
                              hipStream_t stream) {
    const float* Q  = (const float*)d_in[0];
    const float* K  = (const float*)d_in[1];
    const float* V  = (const float*)d_in[2];
    const float* Wq = (const float*)d_in[3];
    const float* Wk = (const float*)d_in[4];
    float* Out = (float*)d_out;

    // workspace: Scs [BH][NC][64][64] fp32 (16 MB) + zc [BH][NC][64] (256 KB)
    float* Scs = (float*)d_ws;
    float* zc  = Scs + (size_t)BH_ * NC_ * 4096;

    dim3 grid(NC_, BH_);
    hipLaunchKernelGGL(ka_chunksum, grid, dim3(256), 0, stream, K, V, Wk, Scs, zc);
    hipLaunchKernelGGL(kp_prefix, dim3(BH_ * 64 + BH_), dim3(64), 0, stream, Scs, zc);
    hipLaunchKernelGGL(kb_attn, grid, dim3(256), 0, stream, Q, K, V, Wq, Wk, Scs, zc, Out);
}

// Round 3
// 121.355 us; speedup vs baseline: 1.0228x; 1.0228x over previous
//
#include <hip/hip_runtime.h>
#include <hip/hip_bf16.h>

// Problem constants (B=2, H=16, L=2048, D=E=64)
#define BH_  32
#define H_   16
#define L_   2048
#define D_   64
#define NC_  32      // number of 64-row chunks per (b,h)
#define STR  72      // LDS row stride in halfs (144 B: 16B-aligned rows, 2-way banks)

typedef _Float16 half8 __attribute__((ext_vector_type(8)));
typedef _Float16 half4 __attribute__((ext_vector_type(4)));
typedef float    floatx4 __attribute__((ext_vector_type(4)));

#define MFMA(a, b, c) __builtin_amdgcn_mfma_f32_16x16x32_f16((a), (b), (c), 0, 0, 0)

// MFMA operand fragment from a row-major [rows][K] LDS matrix (stride STR).
// A-operand: rows = m; B-operand: rows = n (matrix stored as B^T).
// lane layout: row = row0 + (lane&15), k = k0 + (lane>>4)*8 .. +7 (one b128)
__device__ __forceinline__ half8 ldfrag(const _Float16* p, int row0, int k0) {
    const int lane = threadIdx.x & 63;
    const _Float16* q = p + (row0 + (lane & 15)) * STR + k0 + ((lane >> 4) << 3);
    return *(const half8*)q;
}

// ---------------------------------------------------------------------------
// k0: one block per head h. Pre-transpose weights to [e][d] f16:
//   WqTh/WqTl = hi/lo split of Wq^T (split precision for the q feature map),
//   WkT = Wk^T (single f16 — kf errors cancel in the num/den ratio).
// ---------------------------------------------------------------------------
__global__ __launch_bounds__(256)
void k0_weights(const float* __restrict__ Wq, const float* __restrict__ Wk,
                _Float16* __restrict__ WqTh, _Float16* __restrict__ WqTl,
                _Float16* __restrict__ WkT) {
    __shared__ float sQ[64 * 65];
    __shared__ float sK[64 * 65];
    const int h = blockIdx.x, tid = threadIdx.x;
    const float* Wqg = Wq + (size_t)h * 4096;
    const float* Wkg = Wk + (size_t)h * 4096;
    for (int i = 0; i < 16; ++i) {         // coalesced read, transposed LDS write
        int flat = i * 256 + tid;
        int d = flat >> 6, e = flat & 63;
        sQ[e * 65 + d] = Wqg[flat];
        sK[e * 65 + d] = Wkg[flat];
    }
    __syncthreads();
    for (int i = 0; i < 4; ++i) {          // coalesced 8B global writes
        int flat = i * 1024 + tid * 4;     // [e][d] flat
        int e = flat >> 6, d0 = flat & 63;
        half4 qh, ql, kh;
        #pragma unroll
        for (int j = 0; j < 4; ++j) {
            float qv = sQ[e * 65 + d0 + j];
            _Float16 hi = (_Float16)qv;
            qh[j] = hi; ql[j] = (_Float16)(qv - (float)hi);
            kh[j] = (_Float16)sK[e * 65 + d0 + j];
        }
        *(half4*)(WqTh + (size_t)h * 4096 + flat) = qh;
        *(half4*)(WqTl + (size_t)h * 4096 + flat) = ql;
        *(half4*)(WkT  + (size_t)h * 4096 + flat) = kh;
    }
}

// ---------------------------------------------------------------------------
// ka: block (c, bh):
//   kf = relu(K_chunk @ Wk)            (MFMA, f16; computed ONCE here)
//   S^T_c[e][f] = sum_n V[n][e] kf[n][f]  -> Scs (coalesced fp32)
//   z_c[f]      = sum_n kf[n][f]          -> zc
//   side outputs for kb: kf[n][f] f16, V^T[e][n] f16
// ---------------------------------------------------------------------------
__global__ __launch_bounds__(256, 2)
void ka_chunksum(const float* __restrict__ K, const float* __restrict__ V,
                 const _Float16* __restrict__ WkT,
                 float* __restrict__ Scs, float* __restrict__ zc,
                 _Float16* __restrict__ kf16, _Float16* __restrict__ VT16) {
    __shared__ __align__(16) _Float16 sK  [64 * STR]; // K [n][d] -> kf [n][f]
    __shared__ __align__(16) _Float16 sWkT[64 * STR]; // Wk^T [e][d]
    __shared__ __align__(16) _Float16 sVT [64 * STR]; // V^T [e][n]
    __shared__ __align__(16) _Float16 sKfT[64 * STR]; // kf^T [f][n]

    const int c = blockIdx.x, bh = blockIdx.y, h = bh & (H_ - 1);
    const int tid = threadIdx.x, lane = tid & 63, w = tid >> 6;
    const int quad = lane >> 4, cl = lane & 15;

    const float* Kg = K + ((size_t)bh * L_ + c * 64) * D_;
    const float* Vg = V + ((size_t)bh * L_ + c * 64) * D_;
    const size_t cb = (size_t)bh * NC_ + c;

    for (int i = 0; i < 4; ++i) {          // K, V: vector f32 loads
        int flat = i * 1024 + tid * 4;
        int r = flat >> 6, e0 = flat & 63;
        float4 kv = *(const float4*)(Kg + flat);
        half4 kh = { (_Float16)kv.x, (_Float16)kv.y, (_Float16)kv.z, (_Float16)kv.w };
        *(half4*)(sK + r * STR + e0) = kh;
        float4 vv = *(const float4*)(Vg + flat);       // V transpose: 4 b16 scatters
        sVT[(e0 + 0) * STR + r] = (_Float16)vv.x;
        sVT[(e0 + 1) * STR + r] = (_Float16)vv.y;
        sVT[(e0 + 2) * STR + r] = (_Float16)vv.z;
        sVT[(e0 + 3) * STR + r] = (_Float16)vv.w;
    }
    for (int i = 0; i < 2; ++i) {          // WkT: direct half8
        int flat = i * 2048 + tid * 8;
        int e = flat >> 6, d0 = flat & 63;
        *(half8*)(sWkT + e * STR + d0) = *(const half8*)(WkT + (size_t)h * 4096 + flat);
    }
    __syncthreads();

    // kf = relu(K @ Wk); write kf^T[f][n] and kf[n][f] (own-row alias of sK ok)
    half8 ak0 = ldfrag(sK, w * 16, 0), ak1 = ldfrag(sK, w * 16, 32);
    for (int et = 0; et < 4; ++et) {
        floatx4 acc = {0.f, 0.f, 0.f, 0.f};
        acc = MFMA(ak0, ldfrag(sWkT, et * 16, 0),  acc);
        acc = MFMA(ak1, ldfrag(sWkT, et * 16, 32), acc);
        #pragma unroll
        for (int r = 0; r < 4; ++r) {
            float v = acc[r] > 0.f ? acc[r] : 0.f;
            _Float16 hv = (_Float16)v;
            int n = w * 16 + quad * 4 + r, f = et * 16 + cl;
            sKfT[f * STR + n] = hv;
            sK  [n * STR + f] = hv;
        }
    }
    __syncthreads();

    // side outputs (vector copies)
    for (int i = 0; i < 2; ++i) {
        int flat = i * 2048 + tid * 8;
        int rr = flat >> 6, c0 = flat & 63;
        *(half8*)(kf16 + cb * 4096 + flat) = *(const half8*)(sK  + rr * STR + c0);
        *(half8*)(VT16 + cb * 4096 + flat) = *(const half8*)(sVT + rr * STR + c0);
    }
    if (tid < 64) {                        // z_c[f]
        float s = 0.f;
        #pragma unroll
        for (int j = 0; j < 8; ++j) {
            half8 hv = *(const half8*)(sKfT + tid * STR + j * 8);
            #pragma unroll
            for (int t = 0; t < 8; ++t) s += (float)hv[t];
        }
        zc[cb * 64 + tid] = s;
    }

    // S^T[e][f]: A = V^T (m=e rows), B = kf^T (n=f rows), k = n
    float* So = Scs + cb * 4096;
    half8 av0 = ldfrag(sVT, w * 16, 0), av1 = ldfrag(sVT, w * 16, 32);
    for (int et = 0; et < 4; ++et) {
        floatx4 acc = {0.f, 0.f, 0.f, 0.f};
        acc = MFMA(av0, ldfrag(sKfT, et * 16, 0),  acc);
        acc = MFMA(av1, ldfrag(sKfT, et * 16, 32), acc);
        #pragma unroll
        for (int r = 0; r < 4; ++r)
            So[(w * 16 + quad * 4 + r) * 64 + et * 16 + cl] = acc[r];
    }
}

// ---------------------------------------------------------------------------
// kp: in-place EXCLUSIVE prefix sum over chunks for Scs (S^T) and zc.
// ---------------------------------------------------------------------------
__global__ __launch_bounds__(64)
void kp_prefix(float* __restrict__ Scs, float* __restrict__ zc) {
    const int bid = blockIdx.x, t = threadIdx.x;
    if (bid < BH_ * 64) {
        const int bh = bid >> 6, d = bid & 63;
        size_t base = (size_t)bh * NC_ * 4096 + (size_t)d * 64 + t;
        float run = 0.f;
        #pragma unroll
        for (int c = 0; c < NC_; ++c) {
            float v = Scs[base + (size_t)c * 4096];
            Scs[base + (size_t)c * 4096] = run;
            run += v;
        }
    } else {
        const int bh = bid - BH_ * 64;
        size_t base = (size_t)bh * NC_ * 64 + t;
        float run = 0.f;
        #pragma unroll
        for (int c = 0; c < NC_; ++c) {
            float v = zc[base + c * 64];
            zc[base + c * 64] = run;
            run += v;
        }
    }
}

// ---------------------------------------------------------------------------
// kb: block (c, bh): split-precision qf, then causal chunk attention.
//   qf = relu((Qh+Ql)@(Wh+Wl))  ~fp32 (6 MFMAs/tile); dq = qf.z from fp32 accs
//   P  = causal qf kf^T (intra-chunk); O = qf@S^T' + P@V; out = O * inv(den)
// ---------------------------------------------------------------------------
__global__ __launch_bounds__(256, 2)
void kb_attn(const float* __restrict__ Q, const _Float16* __restrict__ WqTh,
             const _Float16* __restrict__ WqTl, const _Float16* __restrict__ kf16,
             const _Float16* __restrict__ VT16, const float* __restrict__ Sst,
             const float* __restrict__ zs, float* __restrict__ Out) {
    __shared__ __align__(16) _Float16 sQh[64 * STR]; // Q hi [m][d] -> qf hi [m][f]
    __shared__ __align__(16) _Float16 sQl[64 * STR]; // Q lo        -> qf lo
    __shared__ __align__(16) _Float16 sWh[64 * STR]; // Wq hi^T [e][d]
    __shared__ __align__(16) _Float16 sWl[64 * STR]; // Wq lo^T -> P [m][n]
    __shared__ __align__(16) _Float16 sKf[64 * STR]; // kf [n][f]
    __shared__ __align__(16) _Float16 sVT[64 * STR]; // V^T [e][n]
    __shared__ __align__(16) _Float16 sST[64 * STR]; // S_prefix^T [e][f]
    __shared__ float sZ[64];

    const int c = blockIdx.x, bh = blockIdx.y, h = bh & (H_ - 1);
    const int tid = threadIdx.x, lane = tid & 63, w = tid >> 6;
    const int quad = lane >> 4, cl = lane & 15;

    const float* Qg = Q + ((size_t)bh * L_ + c * 64) * D_;
    const size_t cb = (size_t)bh * NC_ + c;
    const float* Sg = Sst + cb * 4096;

    for (int i = 0; i < 4; ++i) {          // Q (split) + S^T: vector f32 loads
        int flat = i * 1024 + tid * 4;
        int r = flat >> 6, e0 = flat & 63;
        float4 qv = *(const float4*)(Qg + flat);
        half4 qh, ql;
        #pragma unroll
        for (int j = 0; j < 4; ++j) {
            float x = (&qv.x)[j];
            _Float16 hi = (_Float16)x;
            qh[j] = hi; ql[j] = (_Float16)(x - (float)hi);
        }
        *(half4*)(sQh + r * STR + e0) = qh;
        *(half4*)(sQl + r * STR + e0) = ql;
        float4 sv = *(const float4*)(Sg + flat);
        half4 sh = { (_Float16)sv.x, (_Float16)sv.y, (_Float16)sv.z, (_Float16)sv.w };
        *(half4*)(sST + r * STR + e0) = sh;
    }
    for (int i = 0; i < 2; ++i) {          // f16 arrays: direct half8
        int flat = i * 2048 + tid * 8;
        int rr = flat >> 6, c0 = flat & 63;
        *(half8*)(sWh + rr * STR + c0) = *(const half8*)(WqTh + (size_t)h * 4096 + flat);
        *(half8*)(sWl + rr * STR + c0) = *(const half8*)(WqTl + (size_t)h * 4096 + flat);
        *(half8*)(sKf + rr * STR + c0) = *(const half8*)(kf16 + cb * 4096 + flat);
        *(half8*)(sVT + rr * STR + c0) = *(const half8*)(VT16 + cb * 4096 + flat);
    }
    if (tid < 64) sZ[tid] = zs[cb * 64 + tid];
    __syncthreads();

    // qf stage (~fp32): relu, dq from fp32 accs, write qf hi/lo (own rows)
    half8 aqh0 = ldfrag(sQh, w * 16, 0), aqh1 = ldfrag(sQh, w * 16, 32);
    half8 aql0 = ldfrag(sQl, w * 16, 0), aql1 = ldfrag(sQl, w * 16, 32);
    float dq[4] = {0.f, 0.f, 0.f, 0.f};
    for (int et = 0; et < 4; ++et) {
        half8 bh0 = ldfrag(sWh, et * 16, 0), bh1 = ldfrag(sWh, et * 16, 32);
        half8 bl0 = ldfrag(sWl, et * 16, 0), bl1 = ldfrag(sWl, et * 16, 32);
        floatx4 acc = {0.f, 0.f, 0.f, 0.f};
        acc = MFMA(aqh0, bh0, acc);
        acc = MFMA(aqh1, bh1, acc);
        acc = MFMA(aqh0, bl0, acc);
        acc = MFMA(aqh1, bl1, acc);
        acc = MFMA(aql0, bh0, acc);
        acc = MFMA(aql1, bh1, acc);
        float zv = sZ[et * 16 + cl];
        #pragma unroll
        for (int r = 0; r < 4; ++r) {
            float v = acc[r] > 0.f ? acc[r] : 0.f;
            dq[r] += v * zv;
            _Float16 hi = (_Float16)v;
            int row = w * 16 + quad * 4 + r, col = et * 16 + cl;
            sQh[row * STR + col] = hi;
            sQl[row * STR + col] = (_Float16)(v - (float)hi);
        }
    }
    #pragma unroll
    for (int r = 0; r < 4; ++r) {          // butterfly: all lanes get row total
        dq[r] += __shfl_xor(dq[r], 1);
        dq[r] += __shfl_xor(dq[r], 2);
        dq[r] += __shfl_xor(dq[r], 4);
        dq[r] += __shfl_xor(dq[r], 8);
    }
    __syncthreads();

    // P stage: intra-chunk causal scores + denominators (all in-register)
    half8 qh0 = ldfrag(sQh, w * 16, 0), qh1 = ldfrag(sQh, w * 16, 32);
    half8 ql0 = ldfrag(sQl, w * 16, 0), ql1 = ldfrag(sQl, w * 16, 32);
    _Float16* P = sWl;                     // reuse Wq-lo buffer
    float rs[4] = {0.f, 0.f, 0.f, 0.f};
    float inv[4];
    for (int nt = 0; nt <= w; ++nt) {
        half8 b0 = ldfrag(sKf, nt * 16, 0), b1 = ldfrag(sKf, nt * 16, 32);
        floatx4 acc = {0.f, 0.f, 0.f, 0.f};
        acc = MFMA(qh0, b0, acc);
        acc = MFMA(qh1, b1, acc);
        acc = MFMA(ql0, b0, acc);
        acc = MFMA(ql1, b1, acc);
        #pragma unroll
        for (int r = 0; r < 4; ++r) {
            float v = acc[r];
            if (nt == w && cl > quad * 4 + r) v = 0.f;   // causal mask (diag tile)
            rs[r] += v;
            P[(w * 16 + quad * 4 + r) * STR + nt * 16 + cl] = (_Float16)v;
        }
    }
    for (int nt = w + 1; nt < 4; ++nt) {
        #pragma unroll
        for (int r = 0; r < 4; ++r)
            P[(w * 16 + quad * 4 + r) * STR + nt * 16 + cl] = (_Float16)0.f;
    }
    #pragma unroll
    for (int r = 0; r < 4; ++r) {
        float s = rs[r];
        s += __shfl_xor(s, 1);
        s += __shfl_xor(s, 2);
        s += __shfl_xor(s, 4);
        s += __shfl_xor(s, 8);
        inv[r] = 1.f / (s + dq[r] + 1e-6f);
    }
    __syncthreads();

    // O = (qh+ql)@S^T' + P@V ; scale; store
    half8 p0 = ldfrag(P, w * 16, 0), p1 = ldfrag(P, w * 16, 32);
    float* Og = Out + ((size_t)bh * L_ + c * 64) * D_;
    for (int et = 0; et < 4; ++et) {
        floatx4 acc = {0.f, 0.f, 0.f, 0.f};
        half8 s0 = ldfrag(sST, et * 16, 0), s1 = ldfrag(sST, et * 16, 32);
        acc = MFMA(qh0, s0, acc);
        acc = MFMA(qh1, s1, acc);
        acc = MFMA(ql0, s0, acc);
        acc = MFMA(ql1, s1, acc);
        acc = MFMA(p0, ldfrag(sVT, et * 16, 0),  acc);
        acc = MFMA(p1, ldfrag(sVT, et * 16, 32), acc);
        #pragma unroll
        for (int r = 0; r < 4; ++r)
            Og[(w * 16 + quad * 4 + r) * 64 + et * 16 + cl] = acc[r] * inv[r];
    }
}

// ---------------------------------------------------------------------------
extern "C" void kernel_launch(void* const* d_in, const int* in_sizes, int n_in,
                              void* d_out, int out_size, void* d_ws, size_t ws_size,
                              hipStream_t stream) {
    const float* Q  = (const float*)d_in[0];
    const float* K  = (const float*)d_in[1];
    const float* V  = (const float*)d_in[2];
    const float* Wq = (const float*)d_in[3];
    const float* Wk = (const float*)d_in[4];
    float* Out = (float*)d_out;

    float*    Scs  = (float*)d_ws;                              // 16 MB (S^T)
    float*    zc   = Scs + (size_t)BH_ * NC_ * 4096;            // 256 KB
    _Float16* kf16 = (_Float16*)(zc + (size_t)BH_ * NC_ * 64);  // 8 MB
    _Float16* VT16 = kf16 + (size_t)BH_ * NC_ * 4096;           // 8 MB
    _Float16* WqTh = VT16 + (size_t)BH_ * NC_ * 4096;           // 128 KB
    _Float16* WqTl = WqTh + (size_t)H_ * 4096;                  // 128 KB
    _Float16* WkT  = WqTl + (size_t)H_ * 4096;                  // 128 KB

    dim3 grid(NC_, BH_);
    hipLaunchKernelGGL(k0_weights, dim3(H_), dim3(256), 0, stream, Wq, Wk, WqTh, WqTl, WkT);
    hipLaunchKernelGGL(ka_chunksum, grid, dim3(256), 0, stream, K, V, WkT, Scs, zc, kf16, VT16);
    hipLaunchKernelGGL(kp_prefix, dim3(BH_ * 64 + BH_), dim3(64), 0, stream, Scs, zc);
    hipLaunchKernelGGL(kb_attn, grid, dim3(256), 0, stream, Q, WqTh, WqTl, kf16, VT16, Scs, zc, Out);
}

// Round 4
// 120.564 us; speedup vs baseline: 1.0295x; 1.0066x over previous
//
#include <hip/hip_runtime.h>
#include <hip/hip_bf16.h>

// Problem constants (B=2, H=16, L=2048, D=E=64)
#define BH_  32
#define H_   16
#define L_   2048
#define D_   64
#define NC_  32      // number of 64-row chunks per (b,h)
#define STR  72      // LDS row stride in halfs (144 B: 16B-aligned rows, 2-way banks)

typedef _Float16 half8 __attribute__((ext_vector_type(8)));
typedef _Float16 half4 __attribute__((ext_vector_type(4)));
typedef _Float16 half2v __attribute__((ext_vector_type(2)));
typedef float    floatx4 __attribute__((ext_vector_type(4)));

#define MFMA(a, b, c) __builtin_amdgcn_mfma_f32_16x16x32_f16((a), (b), (c), 0, 0, 0)

// MFMA operand fragment from a row-major [rows][K] LDS matrix (stride STR).
// lane layout: row = row0 + (lane&15), k = k0 + (lane>>4)*8 .. +7 (one b128)
__device__ __forceinline__ half8 ldfrag(const _Float16* p, int row0, int k0) {
    const int lane = threadIdx.x & 63;
    const _Float16* q = p + (row0 + (lane & 15)) * STR + k0 + ((lane >> 4) << 3);
    return *(const half8*)q;
}

// ---------------------------------------------------------------------------
// k0: one block per head h. Pre-transpose weights to [e][d] f16:
//   WqTh/WqTl = hi/lo split of Wq^T, WkT = Wk^T single f16.
// ---------------------------------------------------------------------------
__global__ __launch_bounds__(256)
void k0_weights(const float* __restrict__ Wq, const float* __restrict__ Wk,
                _Float16* __restrict__ WqTh, _Float16* __restrict__ WqTl,
                _Float16* __restrict__ WkT) {
    __shared__ float sQ[64 * 65];
    __shared__ float sK[64 * 65];
    const int h = blockIdx.x, tid = threadIdx.x;
    const float* Wqg = Wq + (size_t)h * 4096;
    const float* Wkg = Wk + (size_t)h * 4096;
    for (int i = 0; i < 16; ++i) {
        int flat = i * 256 + tid;
        int d = flat >> 6, e = flat & 63;
        sQ[e * 65 + d] = Wqg[flat];
        sK[e * 65 + d] = Wkg[flat];
    }
    __syncthreads();
    for (int i = 0; i < 4; ++i) {
        int flat = i * 1024 + tid * 4;
        int e = flat >> 6, d0 = flat & 63;
        half4 qh, ql, kh;
        #pragma unroll
        for (int j = 0; j < 4; ++j) {
            float qv = sQ[e * 65 + d0 + j];
            _Float16 hi = (_Float16)qv;
            qh[j] = hi; ql[j] = (_Float16)(qv - (float)hi);
            kh[j] = (_Float16)sK[e * 65 + d0 + j];
        }
        *(half4*)(WqTh + (size_t)h * 4096 + flat) = qh;
        *(half4*)(WqTl + (size_t)h * 4096 + flat) = ql;
        *(half4*)(WkT  + (size_t)h * 4096 + flat) = kh;
    }
}

// ---------------------------------------------------------------------------
// ka: block (c, bh): kf = relu(K@Wk); S^T_c[e][f] f16, z_c[f] f32,
//     side outputs kf[n][f] f16 and V^T[e][n] f16 for kb.
// ---------------------------------------------------------------------------
__global__ __launch_bounds__(256, 2)
void ka_chunksum(const float* __restrict__ K, const float* __restrict__ V,
                 const _Float16* __restrict__ WkT,
                 _Float16* __restrict__ Ss, float* __restrict__ zc,
                 _Float16* __restrict__ kf16, _Float16* __restrict__ VT16) {
    __shared__ __align__(16) _Float16 sK  [64 * STR]; // K [n][d] -> kf [n][f]
    __shared__ __align__(16) _Float16 sWkT[64 * STR]; // Wk^T [e][d]
    __shared__ __align__(16) _Float16 sVT [64 * STR]; // V^T [e][n]
    __shared__ __align__(16) _Float16 sKfT[64 * STR]; // kf^T [f][n]

    const int c = blockIdx.x, bh = blockIdx.y, h = bh & (H_ - 1);
    const int tid = threadIdx.x, lane = tid & 63, w = tid >> 6;
    const int quad = lane >> 4, cl = lane & 15;

    const float* Kg = K + ((size_t)bh * L_ + c * 64) * D_;
    const float* Vg = V + ((size_t)bh * L_ + c * 64) * D_;
    const size_t cb = (size_t)bh * NC_ + c;

    for (int i = 0; i < 4; ++i) {
        int flat = i * 1024 + tid * 4;
        int r = flat >> 6, e0 = flat & 63;
        float4 kv = *(const float4*)(Kg + flat);
        half4 kh = { (_Float16)kv.x, (_Float16)kv.y, (_Float16)kv.z, (_Float16)kv.w };
        *(half4*)(sK + r * STR + e0) = kh;
        float4 vv = *(const float4*)(Vg + flat);
        sVT[(e0 + 0) * STR + r] = (_Float16)vv.x;
        sVT[(e0 + 1) * STR + r] = (_Float16)vv.y;
        sVT[(e0 + 2) * STR + r] = (_Float16)vv.z;
        sVT[(e0 + 3) * STR + r] = (_Float16)vv.w;
    }
    for (int i = 0; i < 2; ++i) {
        int flat = i * 2048 + tid * 8;
        int e = flat >> 6, d0 = flat & 63;
        *(half8*)(sWkT + e * STR + d0) = *(const half8*)(WkT + (size_t)h * 4096 + flat);
    }
    __syncthreads();

    half8 ak0 = ldfrag(sK, w * 16, 0), ak1 = ldfrag(sK, w * 16, 32);
    for (int et = 0; et < 4; ++et) {
        floatx4 acc = {0.f, 0.f, 0.f, 0.f};
        acc = MFMA(ak0, ldfrag(sWkT, et * 16, 0),  acc);
        acc = MFMA(ak1, ldfrag(sWkT, et * 16, 32), acc);
        #pragma unroll
        for (int r = 0; r < 4; ++r) {
            float v = acc[r] > 0.f ? acc[r] : 0.f;
            _Float16 hv = (_Float16)v;
            int n = w * 16 + quad * 4 + r, f = et * 16 + cl;
            sKfT[f * STR + n] = hv;
            sK  [n * STR + f] = hv;
        }
    }
    __syncthreads();

    for (int i = 0; i < 2; ++i) {          // side outputs (vector copies)
        int flat = i * 2048 + tid * 8;
        int rr = flat >> 6, c0 = flat & 63;
        *(half8*)(kf16 + cb * 4096 + flat) = *(const half8*)(sK  + rr * STR + c0);
        *(half8*)(VT16 + cb * 4096 + flat) = *(const half8*)(sVT + rr * STR + c0);
    }
    if (tid < 64) {                        // z_c[f]
        float s = 0.f;
        #pragma unroll
        for (int j = 0; j < 8; ++j) {
            half8 hv = *(const half8*)(sKfT + tid * STR + j * 8);
            #pragma unroll
            for (int t = 0; t < 8; ++t) s += (float)hv[t];
        }
        zc[cb * 64 + tid] = s;
    }

    // S^T[e][f] f16: A = V^T (m=e rows), B = kf^T (n=f rows), k = n
    _Float16* So = Ss + cb * 4096;
    half8 av0 = ldfrag(sVT, w * 16, 0), av1 = ldfrag(sVT, w * 16, 32);
    for (int et = 0; et < 4; ++et) {
        floatx4 acc = {0.f, 0.f, 0.f, 0.f};
        acc = MFMA(av0, ldfrag(sKfT, et * 16, 0),  acc);
        acc = MFMA(av1, ldfrag(sKfT, et * 16, 32), acc);
        #pragma unroll
        for (int r = 0; r < 4; ++r)
            So[(w * 16 + quad * 4 + r) * 64 + et * 16 + cl] = (_Float16)acc[r];
    }
}

// ---------------------------------------------------------------------------
// kp: in-place EXCLUSIVE prefix over chunks. S rows processed as packed
// uint32 (2 f16 cols) for coalescing; accumulate fp32, store f16.
// blocks [0, BH_*32): (bh, row-pair) of S; [BH_*32, BH_*32+BH_): z (f32).
// ---------------------------------------------------------------------------
__global__ __launch_bounds__(64)
void kp_prefix(_Float16* __restrict__ Ss, float* __restrict__ zc) {
    const int bid = blockIdx.x, t = threadIdx.x;
    if (bid < BH_ * 32) {
        const int bh = bid >> 5, dq = bid & 31;
        uint32_t* S32 = (uint32_t*)Ss;
        size_t base = (size_t)bh * NC_ * 2048 + dq * 64 + t;
        float r0 = 0.f, r1 = 0.f;
        #pragma unroll
        for (int c = 0; c < NC_; ++c) {
            uint32_t u = S32[base + (size_t)c * 2048];
            half2v hv = *(half2v*)&u;
            float v0 = (float)hv[0], v1 = (float)hv[1];
            half2v o; o[0] = (_Float16)r0; o[1] = (_Float16)r1;
            S32[base + (size_t)c * 2048] = *(uint32_t*)&o;
            r0 += v0; r1 += v1;
        }
    } else {
        const int bh = bid - BH_ * 32;
        size_t base = (size_t)bh * NC_ * 64 + t;
        float run = 0.f;
        #pragma unroll
        for (int c = 0; c < NC_; ++c) {
            float v = zc[base + c * 64];
            zc[base + c * 64] = run;
            run += v;
        }
    }
}

// ---------------------------------------------------------------------------
// kb: block (c, bh). ONE barrier. qf split-precision (6 MFMAs/tile) then
// stored single-f16 (row-proportional error cancels in num/den ratio).
// P buffer reuses sQl. S^T/V^T B-fragments loaded global->reg in O loop.
// ---------------------------------------------------------------------------
__global__ __launch_bounds__(256, 3)
void kb_attn(const float* __restrict__ Q, const _Float16* __restrict__ WqTh,
             const _Float16* __restrict__ WqTl, const _Float16* __restrict__ kf16,
             const _Float16* __restrict__ VT16, const _Float16* __restrict__ Ss,
             const float* __restrict__ zs, float* __restrict__ Out) {
    __shared__ __align__(16) _Float16 sQh[64 * STR]; // Q hi [m][d] -> qf f16 [m][f]
    __shared__ __align__(16) _Float16 sQl[64 * STR]; // Q lo [m][d] -> P [m][n]
    __shared__ __align__(16) _Float16 sWh[64 * STR]; // Wq hi^T [e][d]
    __shared__ __align__(16) _Float16 sWl[64 * STR]; // Wq lo^T [e][d]
    __shared__ __align__(16) _Float16 sKf[64 * STR]; // kf [n][f]
    __shared__ float sZ[64];

    const int c = blockIdx.x, bh = blockIdx.y, h = bh & (H_ - 1);
    const int tid = threadIdx.x, lane = tid & 63, w = tid >> 6;
    const int quad = lane >> 4, cl = lane & 15;

    const float* Qg = Q + ((size_t)bh * L_ + c * 64) * D_;
    const size_t cb = (size_t)bh * NC_ + c;
    const _Float16* Sgp = Ss   + cb * 4096;   // S_prefix^T [e][f], stride 64
    const _Float16* Vgp = VT16 + cb * 4096;   // V^T [e][n], stride 64

    for (int i = 0; i < 4; ++i) {             // Q split: vector f32 loads
        int flat = i * 1024 + tid * 4;
        int r = flat >> 6, e0 = flat & 63;
        float4 qv = *(const float4*)(Qg + flat);
        half4 qh, ql;
        #pragma unroll
        for (int j = 0; j < 4; ++j) {
            float x = (&qv.x)[j];
            _Float16 hi = (_Float16)x;
            qh[j] = hi; ql[j] = (_Float16)(x - (float)hi);
        }
        *(half4*)(sQh + r * STR + e0) = qh;
        *(half4*)(sQl + r * STR + e0) = ql;
    }
    for (int i = 0; i < 2; ++i) {             // f16 arrays: direct half8
        int flat = i * 2048 + tid * 8;
        int rr = flat >> 6, c0 = flat & 63;
        *(half8*)(sWh + rr * STR + c0) = *(const half8*)(WqTh + (size_t)h * 4096 + flat);
        *(half8*)(sWl + rr * STR + c0) = *(const half8*)(WqTl + (size_t)h * 4096 + flat);
        *(half8*)(sKf + rr * STR + c0) = *(const half8*)(kf16 + cb * 4096 + flat);
    }
    if (tid < 64) sZ[tid] = zs[cb * 64 + tid];
    __syncthreads();   // the ONLY barrier: everything below is own-row or read-only

    // qf stage (~fp32): relu; dq from fp32 accs; store qf single f16 (own rows)
    half8 aqh0 = ldfrag(sQh, w * 16, 0), aqh1 = ldfrag(sQh, w * 16, 32);
    half8 aql0 = ldfrag(sQl, w * 16, 0), aql1 = ldfrag(sQl, w * 16, 32);
    float dq[4] = {0.f, 0.f, 0.f, 0.f};
    for (int et = 0; et < 4; ++et) {
        half8 bh0 = ldfrag(sWh, et * 16, 0), bh1 = ldfrag(sWh, et * 16, 32);
        half8 bl0 = ldfrag(sWl, et * 16, 0), bl1 = ldfrag(sWl, et * 16, 32);
        floatx4 acc = {0.f, 0.f, 0.f, 0.f};
        acc = MFMA(aqh0, bh0, acc);
        acc = MFMA(aqh1, bh1, acc);
        acc = MFMA(aqh0, bl0, acc);
        acc = MFMA(aqh1, bl1, acc);
        acc = MFMA(aql0, bh0, acc);
        acc = MFMA(aql1, bh1, acc);
        float zv = sZ[et * 16 + cl];
        #pragma unroll
        for (int r = 0; r < 4; ++r) {
            float v = acc[r] > 0.f ? acc[r] : 0.f;
            dq[r] += v * zv;
            sQh[(w * 16 + quad * 4 + r) * STR + et * 16 + cl] = (_Float16)v;
        }
    }
    #pragma unroll
    for (int r = 0; r < 4; ++r) {
        dq[r] += __shfl_xor(dq[r], 1);
        dq[r] += __shfl_xor(dq[r], 2);
        dq[r] += __shfl_xor(dq[r], 4);
        dq[r] += __shfl_xor(dq[r], 8);
    }

    // P stage: intra-chunk causal scores (own rows of P = sQl)
    half8 qh0 = ldfrag(sQh, w * 16, 0), qh1 = ldfrag(sQh, w * 16, 32);
    _Float16* P = sQl;
    float rs[4] = {0.f, 0.f, 0.f, 0.f};
    float inv[4];
    for (int nt = 0; nt <= w; ++nt) {
        floatx4 acc = {0.f, 0.f, 0.f, 0.f};
        acc = MFMA(qh0, ldfrag(sKf, nt * 16, 0),  acc);
        acc = MFMA(qh1, ldfrag(sKf, nt * 16, 32), acc);
        #pragma unroll
        for (int r = 0; r < 4; ++r) {
            float v = acc[r];
            if (nt == w && cl > quad * 4 + r) v = 0.f;   // causal mask (diag tile)
            rs[r] += v;
            P[(w * 16 + quad * 4 + r) * STR + nt * 16 + cl] = (_Float16)v;
        }
    }
    for (int nt = w + 1; nt < 4; ++nt) {
        #pragma unroll
        for (int r = 0; r < 4; ++r)
            P[(w * 16 + quad * 4 + r) * STR + nt * 16 + cl] = (_Float16)0.f;
    }
    #pragma unroll
    for (int r = 0; r < 4; ++r) {
        float s = rs[r];
        s += __shfl_xor(s, 1);
        s += __shfl_xor(s, 2);
        s += __shfl_xor(s, 4);
        s += __shfl_xor(s, 8);
        inv[r] = 1.f / (s + dq[r] + 1e-6f);
    }

    // O stage: O = qf@S^T' + P@V. S^T/V^T fragments direct global->reg
    // (B-fragment: row = et*16 + cl, k = quad*8 (+0/+32); 16B aligned).
    half8 p0 = ldfrag(P, w * 16, 0), p1 = ldfrag(P, w * 16, 32);
    float* Og = Out + ((size_t)bh * L_ + c * 64) * D_;
    for (int et = 0; et < 4; ++et) {
        const _Float16* srow = Sgp + (et * 16 + cl) * 64 + quad * 8;
        const _Float16* vrow = Vgp + (et * 16 + cl) * 64 + quad * 8;
        half8 s0 = *(const half8*)(srow);
        half8 s1 = *(const half8*)(srow + 32);
        half8 v0 = *(const half8*)(vrow);
        half8 v1 = *(const half8*)(vrow + 32);
        floatx4 acc = {0.f, 0.f, 0.f, 0.f};
        acc = MFMA(qh0, s0, acc);
        acc = MFMA(qh1, s1, acc);
        acc = MFMA(p0,  v0, acc);
        acc = MFMA(p1,  v1, acc);
        #pragma unroll
        for (int r = 0; r < 4; ++r)
            Og[(w * 16 + quad * 4 + r) * 64 + et * 16 + cl] = acc[r] * inv[r];
    }
}

// ---------------------------------------------------------------------------
extern "C" void kernel_launch(void* const* d_in, const int* in_sizes, int n_in,
                              void* d_out, int out_size, void* d_ws, size_t ws_size,
                              hipStream_t stream) {
    const float* Q  = (const float*)d_in[0];
    const float* K  = (const float*)d_in[1];
    const float* V  = (const float*)d_in[2];
    const float* Wq = (const float*)d_in[3];
    const float* Wk = (const float*)d_in[4];
    float* Out = (float*)d_out;

    _Float16* Ss   = (_Float16*)d_ws;                            // 8 MB  (S^T f16)
    float*    zc   = (float*)(Ss + (size_t)BH_ * NC_ * 4096);    // 256 KB
    _Float16* kf16 = (_Float16*)(zc + (size_t)BH_ * NC_ * 64);   // 8 MB
    _Float16* VT16 = kf16 + (size_t)BH_ * NC_ * 4096;            // 8 MB
    _Float16* WqTh = VT16 + (size_t)BH_ * NC_ * 4096;            // 128 KB
    _Float16* WqTl = WqTh + (size_t)H_ * 4096;                   // 128 KB
    _Float16* WkT  = WqTl + (size_t)H_ * 4096;                   // 128 KB

    dim3 grid(NC_, BH_);
    hipLaunchKernelGGL(k0_weights, dim3(H_), dim3(256), 0, stream, Wq, Wk, WqTh, WqTl, WkT);
    hipLaunchKernelGGL(ka_chunksum, grid, dim3(256), 0, stream, K, V, WkT, Ss, zc, kf16, VT16);
    hipLaunchKernelGGL(kp_prefix, dim3(BH_ * 32 + BH_), dim3(64), 0, stream, Ss, zc);
    hipLaunchKernelGGL(kb_attn, grid, dim3(256), 0, stream, Q, WqTh, WqTl, kf16, VT16, Ss, zc, Out);
}